// Round 2
// baseline (318.560 us; speedup 1.0000x reference)
//
#include <hip/hip_runtime.h>
#include <hip/hip_bf16.h>
#include <hip/hip_fp16.h>
#include <math.h>

#define D 128
#define BIN_SHIFT 9      // 512 rows per coarse bin
#define BIN_ROWS 512
#define NB_MAX 256       // >= nbins (196 for 100k nodes)
#define CPAD 16          // ints; one 64B line per coarse cursor
#define AW 8192          // edges per stage-A block window
#define BCAP 12288       // binB LDS sort capacity (mean bin = 8192, +45 sigma)

typedef _Float16 half8 __attribute__((ext_vector_type(8)));
typedef float floatx4 __attribute__((ext_vector_type(4)));

// ---------------- W transpose + fp16 convert: wt[n][k] = f16(W[k][n]) ------
// Also zeroes the coarse-bin counters (block 0) so no memset dispatch needed.
__global__ void gcn_wt_kernel(const float* __restrict__ W,
                              unsigned short* __restrict__ wt,
                              int* __restrict__ cbin) {
    const int i = blockIdx.x * 256 + threadIdx.x;  // i = n*128 + k
    const int n = i >> 7, k = i & 127;
    wt[i] = __half_as_ushort(__float2half_rn(W[k * D + n]));
    if (blockIdx.x == 0) cbin[threadIdx.x] = 0;    // NB_MAX == 256
}

// ---------------- GEMM: support_f16 = fp16(x @ W), f16 MFMA ----------------
// No LDS. Each wave: 32 rows x 128 cols. A-frags straight from fp32 x
// (converted in-register), B-frags from wt (L1/L2-hot half8 loads).
// MFMA 16x16x32_f16: A[m=lane&15][k=quad*8+j]; B[k=quad*8+j][n=lane&15];
// D: row=quad*4+reg, col=lane&15 (verified layouts).
__global__ __launch_bounds__(256) void gcn_gemm_kernel(
        const float* __restrict__ x, const unsigned short* __restrict__ wt,
        unsigned short* __restrict__ support2, int n_nodes) {
    const int wave = threadIdx.x >> 6;
    const int lane = threadIdx.x & 63;
    const int q = lane >> 4;      // 0..3
    const int n16 = lane & 15;    // 0..15
    const int row_base = blockIdx.x * 128 + wave * 32;  // 32 rows per wave
    if (row_base >= n_nodes) return;   // 32 | 100000, no partial waves

    const half8* wt8 = (const half8*)wt;  // 16 B = 8 halves; wt row = 16 half8

    floatx4 acc[2][8];
#pragma unroll
    for (int mt = 0; mt < 2; ++mt)
#pragma unroll
        for (int nt = 0; nt < 8; ++nt) acc[mt][nt] = (floatx4){0.f, 0.f, 0.f, 0.f};

#pragma unroll
    for (int kc = 0; kc < 4; ++kc) {
        half8 b[8];
#pragma unroll
        for (int nt = 0; nt < 8; ++nt)
            b[nt] = wt8[(nt * 16 + n16) * 16 + kc * 4 + q];
#pragma unroll
        for (int mt = 0; mt < 2; ++mt) {
            const float* xp = x + (size_t)(row_base + mt * 16 + n16) * D
                                + kc * 32 + q * 8;
            const float4 f0 = *(const float4*)xp;
            const float4 f1 = *(const float4*)(xp + 4);
            half8 a;
            a[0] = (_Float16)f0.x; a[1] = (_Float16)f0.y;
            a[2] = (_Float16)f0.z; a[3] = (_Float16)f0.w;
            a[4] = (_Float16)f1.x; a[5] = (_Float16)f1.y;
            a[6] = (_Float16)f1.z; a[7] = (_Float16)f1.w;
#pragma unroll
            for (int nt = 0; nt < 8; ++nt)
                acc[mt][nt] = __builtin_amdgcn_mfma_f32_16x16x32_f16(
                    a, b[nt], acc[mt][nt], 0, 0, 0);
        }
    }

    // Epilogue: D[row=quad*4+i][col=n16] per reg i -> fp16 stores.
#pragma unroll
    for (int mt = 0; mt < 2; ++mt) {
        const int r0 = row_base + mt * 16 + q * 4;
#pragma unroll
        for (int nt = 0; nt < 8; ++nt) {
            const int col = nt * 16 + n16;
#pragma unroll
            for (int i = 0; i < 4; ++i)
                support2[(size_t)(r0 + i) * D + col] =
                    __half_as_ushort(__float2half_rn(acc[mt][nt][i]));
        }
    }
}

// ---------------- coarse-bin histogram (196 bins), LDS-aggregated ----------
__global__ __launch_bounds__(256) void gcn_chist_kernel(
        const int* __restrict__ erow, int* __restrict__ cbin, int n_edges) {
    __shared__ int h[NB_MAX];
    const int t = threadIdx.x;
    h[t] = 0;
    __syncthreads();
    const int stride = gridDim.x * 256 * 4;
    const int nv = n_edges & ~3;
    for (int i = (blockIdx.x * 256 + t) * 4; i + 3 < n_edges; i += stride) {
        const int4 r = *(const int4*)(erow + i);
        atomicAdd(&h[r.x >> BIN_SHIFT], 1);
        atomicAdd(&h[r.y >> BIN_SHIFT], 1);
        atomicAdd(&h[r.z >> BIN_SHIFT], 1);
        atomicAdd(&h[r.w >> BIN_SHIFT], 1);
    }
    if (blockIdx.x == 0) {  // scalar tail (none for 1.6M, kept for safety)
        for (int i = nv + t; i < n_edges; i += 256)
            atomicAdd(&h[erow[i] >> BIN_SHIFT], 1);
    }
    __syncthreads();
    if (h[t] > 0) atomicAdd(&cbin[t], h[t]);
}

// ---------------- scan of 196 coarse-bin totals (single block) -------------
__global__ void gcn_cscan_kernel(const int* __restrict__ cbin,
                                 int* __restrict__ cbase,
                                 int* __restrict__ ccur,
                                 int* __restrict__ offsets,
                                 int nbins, int n_nodes, int n_edges) {
    __shared__ int sm[256];
    const int t = threadIdx.x;
    const int v = (t < nbins) ? cbin[t] : 0;
    sm[t] = v;
    __syncthreads();
    for (int off = 1; off < 256; off <<= 1) {
        int tv = (t >= off) ? sm[t - off] : 0;
        __syncthreads();
        sm[t] += tv;
        __syncthreads();
    }
    const int ex = sm[t] - v;
    if (t < nbins) { cbase[t] = ex; ccur[t * CPAD] = ex; }
    if (t == 0) { cbase[nbins] = n_edges; offsets[n_nodes] = n_edges; }
}

// ---------------- Stage A: block-local counting sort into coarse bins ----
__global__ __launch_bounds__(256) void gcn_binA_kernel(
        const int* __restrict__ erow, const int* __restrict__ ecol,
        const float* __restrict__ eval, int* __restrict__ ccur,
        uint2* __restrict__ tmp8, int n_edges, int nbins) {
    __shared__ uint2 recs[AW];      // 64 KB
    __shared__ int hist[NB_MAX];
    __shared__ int lstart[NB_MAX];
    __shared__ int gbase[NB_MAX];
    const int t = threadIdx.x;
    const int w0 = blockIdx.x * AW;
    const int wend = min(w0 + AW, n_edges);
    const int cnt = wend - w0;

    for (int i = t; i < NB_MAX; i += 256) hist[i] = 0;
    __syncthreads();

    for (int i = w0 + t; i < wend; i += 256)
        atomicAdd(&hist[erow[i] >> BIN_SHIFT], 1);
    __syncthreads();

    {
        const int v = hist[t];
        gbase[t] = v;
        __syncthreads();
        for (int off = 1; off < 256; off <<= 1) {
            int tv = (t >= off) ? gbase[t - off] : 0;
            __syncthreads();
            gbase[t] += tv;
            __syncthreads();
        }
        lstart[t] = gbase[t] - v;
        __syncthreads();
    }

    {
        const int c = hist[t];
        int gb = 0;
        if (t < nbins && c > 0) gb = atomicAdd(&ccur[t * CPAD], c);
        __syncthreads();
        gbase[t] = gb;
        hist[t] = lstart[t];
    }
    __syncthreads();

    for (int i = w0 + t; i < wend; i += 256) {
        const int r = erow[i];
        const int c = ecol[i];
        const unsigned short vh = __half_as_ushort(__float2half_rn(eval[i]));
        const int b = r >> BIN_SHIFT;
        const int p = atomicAdd(&hist[b], 1);
        recs[p] = make_uint2(((unsigned)r << 15) | vh, (unsigned)c);
    }
    __syncthreads();

    for (int s = t; s < cnt; s += 256) {
        const uint2 rec = recs[s];
        const int b = (int)(rec.x >> 15) >> BIN_SHIFT;
        tmp8[gbase[b] + (s - lstart[b])] = rec;
    }
}

// ---------------- Stage B: count + scan + LDS placement + per-row col-sort -
// Produces per-row offsets AND emits each row's records sorted by col
// (record = (col<<15)|val15, so u32 compare == col compare). Col-sorted
// edge lists make the gather's instantaneous read window ~1/avg_degree of
// support2 (~1.6-3 MB), which fits per-XCD L2 -> gather becomes L2-hit.
// rec4 write is now coalesced (was scattered). Capacity fallback keeps
// correctness for oversized bins (never triggers for Poisson(16) rows).
__global__ __launch_bounds__(256) void gcn_binB_kernel(
        const uint2* __restrict__ tmp8, const int* __restrict__ cbase,
        int* __restrict__ offsets,
        unsigned int* __restrict__ rec4, int n_nodes) {
    __shared__ int cnt[BIN_ROWS];      // per-row counters, then cursors
    __shared__ int rstart[BIN_ROWS];   // per-row local segment starts
    __shared__ int sm[256];
    __shared__ unsigned lrec[BCAP];    // 48 KB local record buffer
    const int bin = blockIdx.x;
    const int r0 = bin << BIN_SHIFT;
    const int t = threadIdx.x;
    cnt[t] = 0;
    cnt[t + 256] = 0;
    __syncthreads();

    const int beg = cbase[bin];
    const int end = cbase[bin + 1];
    const int m = end - beg;

    // pass 1: per-row histogram within the bin
    for (int i = beg + t; i < end; i += 256)
        atomicAdd(&cnt[(int)(tmp8[i].x >> 15) - r0], 1);
    __syncthreads();

    // exclusive scan over 512 counters (2 per thread)
    const int c0 = cnt[2 * t], c1 = cnt[2 * t + 1];
    const int s = c0 + c1;
    sm[t] = s;
    __syncthreads();
    for (int off = 1; off < 256; off <<= 1) {
        int tv = (t >= off) ? sm[t - off] : 0;
        __syncthreads();
        sm[t] += tv;
        __syncthreads();
    }
    const int lofs = sm[t] - s;        // local exclusive prefix for row 2t

    // publish per-row CSR offsets
    const int row0 = r0 + 2 * t;
    if (row0 < n_nodes) offsets[row0] = beg + lofs;
    if (row0 + 1 < n_nodes) offsets[row0 + 1] = beg + lofs + c0;

    if (m <= BCAP) {
        rstart[2 * t] = lofs;
        rstart[2 * t + 1] = lofs + c0;
        cnt[2 * t] = lofs;
        cnt[2 * t + 1] = lofs + c0;
        __syncthreads();

        // pass 2: placement into LDS at local positions
        for (int i = beg + t; i < end; i += 256) {
            const uint2 p = tmp8[i];
            const int r = (int)(p.x >> 15);
            const int pos = atomicAdd(&cnt[r - r0], 1);
            lrec[pos] = (p.y << 15) | (p.x & 0x7FFFu);
        }
        __syncthreads();

        // per-row insertion sort (record MSBs = col); 2 rows per thread.
        // post-placement cnt[j] == end of row j's segment.
#pragma unroll
        for (int jj = 0; jj < 2; ++jj) {
            const int j = 2 * t + jj;
            const int s0 = rstart[j], e0 = cnt[j];
            for (int a = s0 + 1; a < e0; ++a) {
                const unsigned key = lrec[a];
                int b = a - 1;
                while (b >= s0 && lrec[b] > key) { lrec[b + 1] = lrec[b]; --b; }
                lrec[b + 1] = key;
            }
        }
        __syncthreads();

        // coalesced write-out
        for (int i = t; i < m; i += 256)
            rec4[beg + i] = lrec[i];
    } else {
        // fallback: direct global placement, unsorted (correctness only)
        cnt[2 * t] = beg + lofs;
        cnt[2 * t + 1] = beg + lofs + c0;
        __syncthreads();
        for (int i = beg + t; i < end; i += 256) {
            const uint2 p = tmp8[i];
            const int r = (int)(p.x >> 15);
            const int pos = atomicAdd(&cnt[r - r0], 1);
            rec4[pos] = (p.y << 15) | (p.x & 0x7FFFu);
        }
    }
}

// ---------------- per-node reduction + fused tanh ----------------
__global__ __launch_bounds__(256) void gcn_gather_kernel(
        const unsigned int* __restrict__ support_u,
        const unsigned int* __restrict__ rec4,
        const int* __restrict__ offsets,
        float* __restrict__ out, int n_nodes) {
    const int node = __builtin_amdgcn_readfirstlane(
        blockIdx.x * 4 + (threadIdx.x >> 6));
    const int lane = threadIdx.x & 63;
    if (node >= n_nodes) return;

    const int beg = offsets[node];
    const int end = offsets[node + 1];

    float ax = 0.f, ay = 0.f, bx = 0.f, by = 0.f;
    int e = beg;
    for (; e + 3 < end; e += 4) {
        const unsigned r0 = rec4[e + 0];
        const unsigned r1 = rec4[e + 1];
        const unsigned r2 = rec4[e + 2];
        const unsigned r3 = rec4[e + 3];
        const unsigned s0 = support_u[(size_t)(r0 >> 15) * 64 + lane];
        const unsigned s1 = support_u[(size_t)(r1 >> 15) * 64 + lane];
        const unsigned s2 = support_u[(size_t)(r2 >> 15) * 64 + lane];
        const unsigned s3 = support_u[(size_t)(r3 >> 15) * 64 + lane];
        const float v0 = __half2float(__ushort_as_half((unsigned short)(r0 & 0x7FFFu)));
        const float v1 = __half2float(__ushort_as_half((unsigned short)(r1 & 0x7FFFu)));
        const float v2 = __half2float(__ushort_as_half((unsigned short)(r2 & 0x7FFFu)));
        const float v3 = __half2float(__ushort_as_half((unsigned short)(r3 & 0x7FFFu)));
        ax += v0 * __half2float(__ushort_as_half((unsigned short)(s0 & 0xFFFFu)));
        ay += v0 * __half2float(__ushort_as_half((unsigned short)(s0 >> 16)));
        bx += v1 * __half2float(__ushort_as_half((unsigned short)(s1 & 0xFFFFu)));
        by += v1 * __half2float(__ushort_as_half((unsigned short)(s1 >> 16)));
        ax += v2 * __half2float(__ushort_as_half((unsigned short)(s2 & 0xFFFFu)));
        ay += v2 * __half2float(__ushort_as_half((unsigned short)(s2 >> 16)));
        bx += v3 * __half2float(__ushort_as_half((unsigned short)(s3 & 0xFFFFu)));
        by += v3 * __half2float(__ushort_as_half((unsigned short)(s3 >> 16)));
    }
    for (; e < end; ++e) {
        const unsigned r = rec4[e];
        const unsigned s = support_u[(size_t)(r >> 15) * 64 + lane];
        const float v = __half2float(__ushort_as_half((unsigned short)(r & 0x7FFFu)));
        ax += v * __half2float(__ushort_as_half((unsigned short)(s & 0xFFFFu)));
        ay += v * __half2float(__ushort_as_half((unsigned short)(s >> 16)));
    }

    float2* out2 = (float2*)out;
    out2[(size_t)node * 64 + lane] = make_float2(tanhf(ax + bx), tanhf(ay + by));
}

extern "C" void kernel_launch(void* const* d_in, const int* in_sizes, int n_in,
                              void* d_out, int out_size, void* d_ws, size_t ws_size,
                              hipStream_t stream) {
    const float* x    = (const float*)d_in[0];
    const float* W    = (const float*)d_in[1];
    const int*   erow = (const int*)d_in[2];
    const int*   ecol = (const int*)d_in[3];
    const float* eval = (const float*)d_in[4];
    float* out = (float*)d_out;

    const int n_nodes = in_sizes[0] / D;   // 100000
    const int n_edges = in_sizes[2];       // 1600000
    const int nbins = (n_nodes + BIN_ROWS - 1) >> BIN_SHIFT;      // 196

    // Workspace layout (16B alignment preserved per chunk)
    unsigned short* support2 = (unsigned short*)d_ws;             // 25.6 MB
    unsigned short* wt = support2 + (size_t)n_nodes * D;          // 32 KB
    uint2* tmp8   = (uint2*)(wt + D * D);                         // 12.8 MB
    unsigned int* rec4 = (unsigned int*)(tmp8 + n_edges);         // 6.4 MB
    int*  offsets = (int*)(rec4 + n_edges);                       // n_nodes+1
    int*  cbin    = offsets + n_nodes + 1;                        // NB_MAX
    int*  cbase   = cbin + NB_MAX;                                // NB_MAX+1
    int*  ccur    = cbase + NB_MAX + 1;                           // nbins*CPAD

    // 1) wt = f16(W^T) (+ zero coarse-bin counters); support = fp16(x @ W)
    gcn_wt_kernel<<<(D * D) / 256, 256, 0, stream>>>(W, wt, cbin);
    gcn_gemm_kernel<<<(n_nodes + 127) / 128, 256, 0, stream>>>(
        x, wt, support2, n_nodes);

    // 2) coarse-bin histogram + tiny scan
    gcn_chist_kernel<<<320, 256, 0, stream>>>(erow, cbin, n_edges);
    gcn_cscan_kernel<<<1, 256, 0, stream>>>(cbin, cbase, ccur, offsets,
                                            nbins, n_nodes, n_edges);

    // 3) two-stage binned CSR build (binB emits offsets + col-sorted rows)
    gcn_binA_kernel<<<(n_edges + AW - 1) / AW, 256, 0, stream>>>(
        erow, ecol, eval, ccur, tmp8, n_edges, nbins);
    gcn_binB_kernel<<<nbins, 256, 0, stream>>>(tmp8, cbase, offsets, rec4, n_nodes);

    // 4) per-node reduce + fused tanh
    gcn_gather_kernel<<<(n_nodes + 3) / 4, 256, 0, stream>>>(
        (const unsigned int*)support2, rec4, offsets, out, n_nodes);
}

// Round 4
// 260.942 us; speedup vs baseline: 1.2208x; 1.2208x over previous
//
#include <hip/hip_runtime.h>
#include <hip/hip_bf16.h>
#include <hip/hip_fp16.h>
#include <math.h>

#define D 128
#define BIN_SHIFT 9      // 512 rows per coarse bin
#define BIN_ROWS 512
#define NB_MAX 256       // >= nbins (196 for 100k nodes)
#define CPAD 16          // ints; one 64B line per coarse cursor
#define AW 8192          // edges per stage-A block window
#define NCB 16           // col buckets for coarse col-ordering
#define CB_SHIFT 13      // col>>13 -> 0..12 for 100k nodes (2MB window/bucket)
#define CKEYS (BIN_ROWS * NCB)   // 8192 composite counters (32 KB)

typedef _Float16 half8 __attribute__((ext_vector_type(8)));
typedef float floatx4 __attribute__((ext_vector_type(4)));
typedef float floatx2 __attribute__((ext_vector_type(2)));

// slot mapping for composite counters: bank-transposed so that thread t's
// 32 consecutive keys [32t,32t+32) live at slot (i<<8)|t -> bank t%32,
// making the 8192-wide scan walk conflict-free.
__device__ __forceinline__ int cslot(int k) { return ((k & 31) << 8) | (k >> 5); }

// ---------------- W transpose + fp16 convert: wt[n][k] = f16(W[k][n]) ------
// Also zeroes the coarse-bin counters (block 0) so no memset dispatch needed.
__global__ void gcn_wt_kernel(const float* __restrict__ W,
                              unsigned short* __restrict__ wt,
                              int* __restrict__ cbin) {
    const int i = blockIdx.x * 256 + threadIdx.x;  // i = n*128 + k
    const int n = i >> 7, k = i & 127;
    wt[i] = __half_as_ushort(__float2half_rn(W[k * D + n]));
    if (blockIdx.x == 0) cbin[threadIdx.x] = 0;    // NB_MAX == 256
}

// ---------------- GEMM: support_f16 = fp16(x @ W), f16 MFMA ----------------
__global__ __launch_bounds__(256) void gcn_gemm_kernel(
        const float* __restrict__ x, const unsigned short* __restrict__ wt,
        unsigned short* __restrict__ support2, int n_nodes) {
    const int wave = threadIdx.x >> 6;
    const int lane = threadIdx.x & 63;
    const int q = lane >> 4;      // 0..3
    const int n16 = lane & 15;    // 0..15
    const int row_base = blockIdx.x * 128 + wave * 32;  // 32 rows per wave
    if (row_base >= n_nodes) return;   // 32 | 100000, no partial waves

    const half8* wt8 = (const half8*)wt;  // 16 B = 8 halves; wt row = 16 half8

    floatx4 acc[2][8];
#pragma unroll
    for (int mt = 0; mt < 2; ++mt)
#pragma unroll
        for (int nt = 0; nt < 8; ++nt) acc[mt][nt] = (floatx4){0.f, 0.f, 0.f, 0.f};

#pragma unroll
    for (int kc = 0; kc < 4; ++kc) {
        half8 b[8];
#pragma unroll
        for (int nt = 0; nt < 8; ++nt)
            b[nt] = wt8[(nt * 16 + n16) * 16 + kc * 4 + q];
#pragma unroll
        for (int mt = 0; mt < 2; ++mt) {
            const float* xp = x + (size_t)(row_base + mt * 16 + n16) * D
                                + kc * 32 + q * 8;
            const float4 f0 = *(const float4*)xp;
            const float4 f1 = *(const float4*)(xp + 4);
            half8 a;
            a[0] = (_Float16)f0.x; a[1] = (_Float16)f0.y;
            a[2] = (_Float16)f0.z; a[3] = (_Float16)f0.w;
            a[4] = (_Float16)f1.x; a[5] = (_Float16)f1.y;
            a[6] = (_Float16)f1.z; a[7] = (_Float16)f1.w;
#pragma unroll
            for (int nt = 0; nt < 8; ++nt)
                acc[mt][nt] = __builtin_amdgcn_mfma_f32_16x16x32_f16(
                    a, b[nt], acc[mt][nt], 0, 0, 0);
        }
    }

#pragma unroll
    for (int mt = 0; mt < 2; ++mt) {
        const int r0 = row_base + mt * 16 + q * 4;
#pragma unroll
        for (int nt = 0; nt < 8; ++nt) {
            const int col = nt * 16 + n16;
#pragma unroll
            for (int i = 0; i < 4; ++i)
                support2[(size_t)(r0 + i) * D + col] =
                    __half_as_ushort(__float2half_rn(acc[mt][nt][i]));
        }
    }
}

// ---------------- coarse-bin histogram (196 bins), LDS-aggregated ----------
__global__ __launch_bounds__(256) void gcn_chist_kernel(
        const int* __restrict__ erow, int* __restrict__ cbin, int n_edges) {
    __shared__ int h[NB_MAX];
    const int t = threadIdx.x;
    h[t] = 0;
    __syncthreads();
    const int stride = gridDim.x * 256 * 4;
    const int nv = n_edges & ~3;
    for (int i = (blockIdx.x * 256 + t) * 4; i + 3 < n_edges; i += stride) {
        const int4 r = *(const int4*)(erow + i);
        atomicAdd(&h[r.x >> BIN_SHIFT], 1);
        atomicAdd(&h[r.y >> BIN_SHIFT], 1);
        atomicAdd(&h[r.z >> BIN_SHIFT], 1);
        atomicAdd(&h[r.w >> BIN_SHIFT], 1);
    }
    if (blockIdx.x == 0) {  // scalar tail (none for 1.6M, kept for safety)
        for (int i = nv + t; i < n_edges; i += 256)
            atomicAdd(&h[erow[i] >> BIN_SHIFT], 1);
    }
    __syncthreads();
    if (h[t] > 0) atomicAdd(&cbin[t], h[t]);
}

// ---------------- scan of 196 coarse-bin totals (single block) -------------
__global__ void gcn_cscan_kernel(const int* __restrict__ cbin,
                                 int* __restrict__ cbase,
                                 int* __restrict__ ccur,
                                 int* __restrict__ offsets,
                                 int nbins, int n_nodes, int n_edges) {
    __shared__ int sm[256];
    const int t = threadIdx.x;
    const int v = (t < nbins) ? cbin[t] : 0;
    sm[t] = v;
    __syncthreads();
    for (int off = 1; off < 256; off <<= 1) {
        int tv = (t >= off) ? sm[t - off] : 0;
        __syncthreads();
        sm[t] += tv;
        __syncthreads();
    }
    const int ex = sm[t] - v;
    if (t < nbins) { cbase[t] = ex; ccur[t * CPAD] = ex; }
    if (t == 0) { cbase[nbins] = n_edges; offsets[n_nodes] = n_edges; }
}

// ---------------- Stage A: block-local counting sort into coarse bins ----
__global__ __launch_bounds__(256) void gcn_binA_kernel(
        const int* __restrict__ erow, const int* __restrict__ ecol,
        const float* __restrict__ eval, int* __restrict__ ccur,
        uint2* __restrict__ tmp8, int n_edges, int nbins) {
    __shared__ uint2 recs[AW];      // 64 KB
    __shared__ int hist[NB_MAX];
    __shared__ int lstart[NB_MAX];
    __shared__ int gbase[NB_MAX];
    const int t = threadIdx.x;
    const int w0 = blockIdx.x * AW;
    const int wend = min(w0 + AW, n_edges);
    const int cnt = wend - w0;

    for (int i = t; i < NB_MAX; i += 256) hist[i] = 0;
    __syncthreads();

    for (int i = w0 + t; i < wend; i += 256)
        atomicAdd(&hist[erow[i] >> BIN_SHIFT], 1);
    __syncthreads();

    {
        const int v = hist[t];
        gbase[t] = v;
        __syncthreads();
        for (int off = 1; off < 256; off <<= 1) {
            int tv = (t >= off) ? gbase[t - off] : 0;
            __syncthreads();
            gbase[t] += tv;
            __syncthreads();
        }
        lstart[t] = gbase[t] - v;
        __syncthreads();
    }

    {
        const int c = hist[t];
        int gb = 0;
        if (t < nbins && c > 0) gb = atomicAdd(&ccur[t * CPAD], c);
        __syncthreads();
        gbase[t] = gb;
        hist[t] = lstart[t];
    }
    __syncthreads();

    for (int i = w0 + t; i < wend; i += 256) {
        const int r = erow[i];
        const int c = ecol[i];
        const unsigned short vh = __half_as_ushort(__float2half_rn(eval[i]));
        const int b = r >> BIN_SHIFT;
        const int p = atomicAdd(&hist[b], 1);
        recs[p] = make_uint2(((unsigned)r << 15) | vh, (unsigned)c);
    }
    __syncthreads();

    for (int s = t; s < cnt; s += 256) {
        const uint2 rec = recs[s];
        const int b = (int)(rec.x >> 15) >> BIN_SHIFT;
        tmp8[gbase[b] + (s - lstart[b])] = rec;
    }
}

// ---------------- Stage B: composite-key counting sort + CSR offsets -------
// O(m) counting sort on key = (local_row << 4) | col_bucket. Produces
// per-row CSR offsets AND coarse col-ordering within each row (16 buckets
// of 8192 cols -> gather read window ~2MB, fits per-XCD L2). Direct global
// placement (scattered within the bin's 32KB rec4 slice, L2-absorbed).
// No serial per-row sort, no capacity limit, all phases O(m/256) parallel.
__global__ __launch_bounds__(256) void gcn_binB_kernel(
        const uint2* __restrict__ tmp8, const int* __restrict__ cbase,
        int* __restrict__ offsets,
        unsigned int* __restrict__ rec4, int n_nodes) {
    __shared__ int cnt[CKEYS];     // 32 KB composite counters (bank-transposed)
    __shared__ int sm[256];
    const int bin = blockIdx.x;
    const int r0 = bin << BIN_SHIFT;
    const int t = threadIdx.x;
    for (int i = t; i < CKEYS; i += 256) cnt[i] = 0;
    __syncthreads();

    const int beg = cbase[bin];
    const int end = cbase[bin + 1];

    // pass 1: composite histogram
    for (int i = beg + t; i < end; i += 256) {
        const uint2 p = tmp8[i];
        const int k = (((int)(p.x >> 15) - r0) << 4) | (int)(p.y >> CB_SHIFT);
        atomicAdd(&cnt[cslot(k)], 1);
    }
    __syncthreads();

    // exclusive scan over 8192 counters in key order.
    // thread t owns keys [32t, 32t+32) at slots (i<<8)|t (bank-conflict-free).
    int sum = 0;
#pragma unroll
    for (int i = 0; i < 32; ++i) sum += cnt[(i << 8) | t];
    sm[t] = sum;
    __syncthreads();
    for (int off = 1; off < 256; off <<= 1) {
        int tv = (t >= off) ? sm[t - off] : 0;
        __syncthreads();
        sm[t] += tv;
        __syncthreads();
    }
    int run = sm[t] - sum;
#pragma unroll
    for (int i = 0; i < 32; ++i) {
        const int s = (i << 8) | t;
        const int c = cnt[s];
        cnt[s] = run;
        run += c;
    }
    __syncthreads();

    // per-row CSR offsets: row start = prefix at key (lr<<4 | bucket 0)
    for (int lr = t; lr < BIN_ROWS; lr += 256) {
        const int row = r0 + lr;
        if (row < n_nodes) offsets[row] = beg + cnt[cslot(lr << 4)];
    }
    __syncthreads();

    // pass 2: placement (tmp8 slice L2-hot from pass 1)
    for (int i = beg + t; i < end; i += 256) {
        const uint2 p = tmp8[i];
        const int k = (((int)(p.x >> 15) - r0) << 4) | (int)(p.y >> CB_SHIFT);
        const int pos = beg + atomicAdd(&cnt[cslot(k)], 1);
        rec4[pos] = (p.y << 15) | (p.x & 0x7FFFu);
    }
}

// ---------------- per-node reduction + fused tanh ----------------
__global__ __launch_bounds__(256) void gcn_gather_kernel(
        const unsigned int* __restrict__ support_u,
        const unsigned int* __restrict__ rec4,
        const int* __restrict__ offsets,
        float* __restrict__ out, int n_nodes) {
    const int node = __builtin_amdgcn_readfirstlane(
        blockIdx.x * 4 + (threadIdx.x >> 6));
    const int lane = threadIdx.x & 63;
    if (node >= n_nodes) return;

    const int beg = offsets[node];
    const int end = offsets[node + 1];

    float ax = 0.f, ay = 0.f, bx = 0.f, by = 0.f;
    int e = beg;
    // 8-wide unroll: 8 independent rec4->support dependent chains in flight
    for (; e + 7 < end; e += 8) {
        unsigned r[8], s[8];
#pragma unroll
        for (int j = 0; j < 8; ++j) r[j] = rec4[e + j];
#pragma unroll
        for (int j = 0; j < 8; ++j)
            s[j] = support_u[(size_t)(r[j] >> 15) * 64 + lane];
#pragma unroll
        for (int j = 0; j < 8; ++j) {
            const float v = __half2float(__ushort_as_half((unsigned short)(r[j] & 0x7FFFu)));
            const float slo = __half2float(__ushort_as_half((unsigned short)(s[j] & 0xFFFFu)));
            const float shi = __half2float(__ushort_as_half((unsigned short)(s[j] >> 16)));
            if (j & 1) { bx += v * slo; by += v * shi; }
            else       { ax += v * slo; ay += v * shi; }
        }
    }
    for (; e + 3 < end; e += 4) {
        unsigned r[4], s[4];
#pragma unroll
        for (int j = 0; j < 4; ++j) r[j] = rec4[e + j];
#pragma unroll
        for (int j = 0; j < 4; ++j)
            s[j] = support_u[(size_t)(r[j] >> 15) * 64 + lane];
#pragma unroll
        for (int j = 0; j < 4; ++j) {
            const float v = __half2float(__ushort_as_half((unsigned short)(r[j] & 0x7FFFu)));
            const float slo = __half2float(__ushort_as_half((unsigned short)(s[j] & 0xFFFFu)));
            const float shi = __half2float(__ushort_as_half((unsigned short)(s[j] >> 16)));
            if (j & 1) { bx += v * slo; by += v * shi; }
            else       { ax += v * slo; ay += v * shi; }
        }
    }
    for (; e < end; ++e) {
        const unsigned r = rec4[e];
        const unsigned s = support_u[(size_t)(r >> 15) * 64 + lane];
        const float v = __half2float(__ushort_as_half((unsigned short)(r & 0x7FFFu)));
        ax += v * __half2float(__ushort_as_half((unsigned short)(s & 0xFFFFu)));
        ay += v * __half2float(__ushort_as_half((unsigned short)(s >> 16)));
    }

    // non-temporal: don't let the 50MB out stream evict support rows from L2.
    // (clang ext_vector, not HIP float2 — nontemporal builtin requires it)
    floatx2 res;
    res.x = tanhf(ax + bx);
    res.y = tanhf(ay + by);
    floatx2* out2 = (floatx2*)out;
    __builtin_nontemporal_store(res, &out2[(size_t)node * 64 + lane]);
}

extern "C" void kernel_launch(void* const* d_in, const int* in_sizes, int n_in,
                              void* d_out, int out_size, void* d_ws, size_t ws_size,
                              hipStream_t stream) {
    const float* x    = (const float*)d_in[0];
    const float* W    = (const float*)d_in[1];
    const int*   erow = (const int*)d_in[2];
    const int*   ecol = (const int*)d_in[3];
    const float* eval = (const float*)d_in[4];
    float* out = (float*)d_out;

    const int n_nodes = in_sizes[0] / D;   // 100000
    const int n_edges = in_sizes[2];       // 1600000
    const int nbins = (n_nodes + BIN_ROWS - 1) >> BIN_SHIFT;      // 196

    // Workspace layout (16B alignment preserved per chunk)
    unsigned short* support2 = (unsigned short*)d_ws;             // 25.6 MB
    unsigned short* wt = support2 + (size_t)n_nodes * D;          // 32 KB
    uint2* tmp8   = (uint2*)(wt + D * D);                         // 12.8 MB
    unsigned int* rec4 = (unsigned int*)(tmp8 + n_edges);         // 6.4 MB
    int*  offsets = (int*)(rec4 + n_edges);                       // n_nodes+1
    int*  cbin    = offsets + n_nodes + 1;                        // NB_MAX
    int*  cbase   = cbin + NB_MAX;                                // NB_MAX+1
    int*  ccur    = cbase + NB_MAX + 1;                           // nbins*CPAD

    // 1) wt = f16(W^T) (+ zero coarse-bin counters); support = fp16(x @ W)
    gcn_wt_kernel<<<(D * D) / 256, 256, 0, stream>>>(W, wt, cbin);
    gcn_gemm_kernel<<<(n_nodes + 127) / 128, 256, 0, stream>>>(
        x, wt, support2, n_nodes);

    // 2) coarse-bin histogram + tiny scan
    gcn_chist_kernel<<<320, 256, 0, stream>>>(erow, cbin, n_edges);
    gcn_cscan_kernel<<<1, 256, 0, stream>>>(cbin, cbase, ccur, offsets,
                                            nbins, n_nodes, n_edges);

    // 3) two-stage binned CSR build (binB: counting sort + coarse col-order)
    gcn_binA_kernel<<<(n_edges + AW - 1) / AW, 256, 0, stream>>>(
        erow, ecol, eval, ccur, tmp8, n_edges, nbins);
    gcn_binB_kernel<<<nbins, 256, 0, stream>>>(tmp8, cbase, offsets, rec4, n_nodes);

    // 4) per-node reduce + fused tanh
    gcn_gather_kernel<<<(n_nodes + 3) / 4, 256, 0, stream>>>(
        (const unsigned int*)support2, rec4, offsets, out, n_nodes);
}

// Round 5
// 241.287 us; speedup vs baseline: 1.3203x; 1.0815x over previous
//
#include <hip/hip_runtime.h>
#include <hip/hip_bf16.h>
#include <hip/hip_fp16.h>
#include <math.h>

#define D 128
#define BIN_SHIFT 8      // 256 rows per coarse bin
#define BIN_ROWS 256
#define NB_MAX 512       // >= nbins (391 for 100k nodes)
#define CPAD 16          // ints; one 64B line per coarse cursor
#define AW 4096          // edges per stage-A block window

typedef _Float16 half8 __attribute__((ext_vector_type(8)));
typedef float floatx4 __attribute__((ext_vector_type(4)));
typedef float floatx2 __attribute__((ext_vector_type(2)));

// ---------------- W transpose + fp16 convert: wt[n][k] = f16(W[k][n]) ------
// Blocks 0-1 also zero the 512 coarse-bin counters (no memset dispatch).
__global__ void gcn_wt_kernel(const float* __restrict__ W,
                              unsigned short* __restrict__ wt,
                              int* __restrict__ cbin) {
    const int i = blockIdx.x * 256 + threadIdx.x;  // i = n*128 + k
    const int n = i >> 7, k = i & 127;
    wt[i] = __half_as_ushort(__float2half_rn(W[k * D + n]));
    if (blockIdx.x < 2) cbin[blockIdx.x * 256 + threadIdx.x] = 0;  // NB_MAX=512
}

// ---------------- GEMM: support_f16 = fp16(x @ W), f16 MFMA ----------------
__global__ __launch_bounds__(256) void gcn_gemm_kernel(
        const float* __restrict__ x, const unsigned short* __restrict__ wt,
        unsigned short* __restrict__ support2, int n_nodes) {
    const int wave = threadIdx.x >> 6;
    const int lane = threadIdx.x & 63;
    const int q = lane >> 4;      // 0..3
    const int n16 = lane & 15;    // 0..15
    const int row_base = blockIdx.x * 128 + wave * 32;  // 32 rows per wave
    if (row_base >= n_nodes) return;   // 32 | 100000, no partial waves

    const half8* wt8 = (const half8*)wt;  // 16 B = 8 halves; wt row = 16 half8

    floatx4 acc[2][8];
#pragma unroll
    for (int mt = 0; mt < 2; ++mt)
#pragma unroll
        for (int nt = 0; nt < 8; ++nt) acc[mt][nt] = (floatx4){0.f, 0.f, 0.f, 0.f};

#pragma unroll
    for (int kc = 0; kc < 4; ++kc) {
        half8 b[8];
#pragma unroll
        for (int nt = 0; nt < 8; ++nt)
            b[nt] = wt8[(nt * 16 + n16) * 16 + kc * 4 + q];
#pragma unroll
        for (int mt = 0; mt < 2; ++mt) {
            const float* xp = x + (size_t)(row_base + mt * 16 + n16) * D
                                + kc * 32 + q * 8;
            const float4 f0 = *(const float4*)xp;
            const float4 f1 = *(const float4*)(xp + 4);
            half8 a;
            a[0] = (_Float16)f0.x; a[1] = (_Float16)f0.y;
            a[2] = (_Float16)f0.z; a[3] = (_Float16)f0.w;
            a[4] = (_Float16)f1.x; a[5] = (_Float16)f1.y;
            a[6] = (_Float16)f1.z; a[7] = (_Float16)f1.w;
#pragma unroll
            for (int nt = 0; nt < 8; ++nt)
                acc[mt][nt] = __builtin_amdgcn_mfma_f32_16x16x32_f16(
                    a, b[nt], acc[mt][nt], 0, 0, 0);
        }
    }

#pragma unroll
    for (int mt = 0; mt < 2; ++mt) {
        const int r0 = row_base + mt * 16 + q * 4;
#pragma unroll
        for (int nt = 0; nt < 8; ++nt) {
            const int col = nt * 16 + n16;
#pragma unroll
            for (int i = 0; i < 4; ++i)
                support2[(size_t)(r0 + i) * D + col] =
                    __half_as_ushort(__float2half_rn(acc[mt][nt][i]));
        }
    }
}

// ---------------- coarse-bin histogram (391 bins), LDS-aggregated ----------
__global__ __launch_bounds__(256) void gcn_chist_kernel(
        const int* __restrict__ erow, int* __restrict__ cbin, int n_edges) {
    __shared__ int h[NB_MAX];
    const int t = threadIdx.x;
    h[t] = 0;
    h[t + 256] = 0;
    __syncthreads();
    const int stride = gridDim.x * 256 * 4;
    const int nv = n_edges & ~3;
    for (int i = (blockIdx.x * 256 + t) * 4; i + 3 < n_edges; i += stride) {
        const int4 r = *(const int4*)(erow + i);
        atomicAdd(&h[r.x >> BIN_SHIFT], 1);
        atomicAdd(&h[r.y >> BIN_SHIFT], 1);
        atomicAdd(&h[r.z >> BIN_SHIFT], 1);
        atomicAdd(&h[r.w >> BIN_SHIFT], 1);
    }
    if (blockIdx.x == 0) {  // scalar tail (none for 1.6M, kept for safety)
        for (int i = nv + t; i < n_edges; i += 256)
            atomicAdd(&h[erow[i] >> BIN_SHIFT], 1);
    }
    __syncthreads();
    if (h[t] > 0) atomicAdd(&cbin[t], h[t]);
    if (h[t + 256] > 0) atomicAdd(&cbin[t + 256], h[t + 256]);
}

// ---------------- scan of 391 coarse-bin totals (single block, 512 thr) ----
__global__ __launch_bounds__(512) void gcn_cscan_kernel(
        const int* __restrict__ cbin, int* __restrict__ cbase,
        int* __restrict__ ccur, int* __restrict__ offsets,
        int nbins, int n_nodes, int n_edges) {
    __shared__ int sm[512];
    const int t = threadIdx.x;
    const int v = (t < nbins) ? cbin[t] : 0;
    sm[t] = v;
    __syncthreads();
    for (int off = 1; off < 512; off <<= 1) {
        int tv = (t >= off) ? sm[t - off] : 0;
        __syncthreads();
        sm[t] += tv;
        __syncthreads();
    }
    const int ex = sm[t] - v;
    if (t < nbins) { cbase[t] = ex; ccur[t * CPAD] = ex; }
    if (t == 0) { cbase[nbins] = n_edges; offsets[n_nodes] = n_edges; }
}

// ---------------- Stage A: block-local counting sort into coarse bins ----
// 512 threads, AW=4096 -> 391 blocks, 38 KB LDS (was 196 blocks / 67 KB).
__global__ __launch_bounds__(512) void gcn_binA_kernel(
        const int* __restrict__ erow, const int* __restrict__ ecol,
        const float* __restrict__ eval, int* __restrict__ ccur,
        uint2* __restrict__ tmp8, int n_edges, int nbins) {
    __shared__ uint2 recs[AW];      // 32 KB
    __shared__ int hist[NB_MAX];
    __shared__ int lstart[NB_MAX];
    __shared__ int gbase[NB_MAX];
    const int t = threadIdx.x;
    const int w0 = blockIdx.x * AW;
    const int wend = min(w0 + AW, n_edges);
    const int cnt = wend - w0;

    hist[t] = 0;
    __syncthreads();

    for (int i = w0 + t; i < wend; i += 512)
        atomicAdd(&hist[erow[i] >> BIN_SHIFT], 1);
    __syncthreads();

    {
        const int v = hist[t];
        gbase[t] = v;
        __syncthreads();
        for (int off = 1; off < 512; off <<= 1) {
            int tv = (t >= off) ? gbase[t - off] : 0;
            __syncthreads();
            gbase[t] += tv;
            __syncthreads();
        }
        lstart[t] = gbase[t] - v;
        __syncthreads();
    }

    {
        const int c = hist[t];
        int gb = 0;
        if (t < nbins && c > 0) gb = atomicAdd(&ccur[t * CPAD], c);
        __syncthreads();
        gbase[t] = gb;
        hist[t] = lstart[t];
    }
    __syncthreads();

    for (int i = w0 + t; i < wend; i += 512) {
        const int r = erow[i];
        const int c = ecol[i];
        const unsigned short vh = __half_as_ushort(__float2half_rn(eval[i]));
        const int b = r >> BIN_SHIFT;
        const int p = atomicAdd(&hist[b], 1);
        recs[p] = make_uint2(((unsigned)r << 15) | vh, (unsigned)c);
    }
    __syncthreads();

    for (int s = t; s < cnt; s += 512) {
        const uint2 rec = recs[s];
        const int b = (int)(rec.x >> 15) >> BIN_SHIFT;
        tmp8[gbase[b] + (s - lstart[b])] = rec;
    }
}

// ---------------- Stage B: per-row count + scan + CSR placement ------------
// One 256-row bin per block (391 blocks), one LDS counter per thread.
// Emits per-row CSR offsets and places records (scattered within the bin's
// ~32 KB rec4 slice, L2-absorbed). No serial walks, 1 KB zero-init.
__global__ __launch_bounds__(256) void gcn_binB_kernel(
        const uint2* __restrict__ tmp8, const int* __restrict__ cbase,
        int* __restrict__ offsets,
        unsigned int* __restrict__ rec4, int n_nodes) {
    __shared__ int cnt[BIN_ROWS];
    __shared__ int sm[BIN_ROWS];
    const int bin = blockIdx.x;
    const int r0 = bin << BIN_SHIFT;
    const int t = threadIdx.x;
    cnt[t] = 0;
    __syncthreads();

    const int beg = cbase[bin];
    const int end = cbase[bin + 1];

    // pass 1: per-row histogram within the bin
    for (int i = beg + t; i < end; i += 256)
        atomicAdd(&cnt[(int)(tmp8[i].x >> 15) - r0], 1);
    __syncthreads();

    // exclusive scan over 256 counters (1 per thread)
    const int v = cnt[t];
    sm[t] = v;
    __syncthreads();
    for (int off = 1; off < 256; off <<= 1) {
        int tv = (t >= off) ? sm[t - off] : 0;
        __syncthreads();
        sm[t] += tv;
        __syncthreads();
    }
    const int mypos = beg + sm[t] - v;   // global CSR start for row r0+t

    const int row = r0 + t;
    if (row < n_nodes) offsets[row] = mypos;
    __syncthreads();
    cnt[t] = mypos;                      // per-row cursor
    __syncthreads();

    // pass 2: placement (tmp8 slice L2-hot from pass 1)
    for (int i = beg + t; i < end; i += 256) {
        const uint2 p = tmp8[i];
        const int pos = atomicAdd(&cnt[(int)(p.x >> 15) - r0], 1);
        rec4[pos] = (p.y << 15) | (p.x & 0x7FFFu);
    }
}

// ---------------- per-node reduction + fused tanh ----------------
__global__ __launch_bounds__(256) void gcn_gather_kernel(
        const unsigned int* __restrict__ support_u,
        const unsigned int* __restrict__ rec4,
        const int* __restrict__ offsets,
        float* __restrict__ out, int n_nodes) {
    const int node = __builtin_amdgcn_readfirstlane(
        blockIdx.x * 4 + (threadIdx.x >> 6));
    const int lane = threadIdx.x & 63;
    if (node >= n_nodes) return;

    const int beg = offsets[node];
    const int end = offsets[node + 1];

    float ax = 0.f, ay = 0.f, bx = 0.f, by = 0.f;
    int e = beg;
    // 8-wide unroll: 8 independent rec4->support dependent chains in flight
    for (; e + 7 < end; e += 8) {
        unsigned r[8], s[8];
#pragma unroll
        for (int j = 0; j < 8; ++j) r[j] = rec4[e + j];
#pragma unroll
        for (int j = 0; j < 8; ++j)
            s[j] = support_u[(size_t)(r[j] >> 15) * 64 + lane];
#pragma unroll
        for (int j = 0; j < 8; ++j) {
            const float v = __half2float(__ushort_as_half((unsigned short)(r[j] & 0x7FFFu)));
            const float slo = __half2float(__ushort_as_half((unsigned short)(s[j] & 0xFFFFu)));
            const float shi = __half2float(__ushort_as_half((unsigned short)(s[j] >> 16)));
            if (j & 1) { bx += v * slo; by += v * shi; }
            else       { ax += v * slo; ay += v * shi; }
        }
    }
    for (; e + 3 < end; e += 4) {
        unsigned r[4], s[4];
#pragma unroll
        for (int j = 0; j < 4; ++j) r[j] = rec4[e + j];
#pragma unroll
        for (int j = 0; j < 4; ++j)
            s[j] = support_u[(size_t)(r[j] >> 15) * 64 + lane];
#pragma unroll
        for (int j = 0; j < 4; ++j) {
            const float v = __half2float(__ushort_as_half((unsigned short)(r[j] & 0x7FFFu)));
            const float slo = __half2float(__ushort_as_half((unsigned short)(s[j] & 0xFFFFu)));
            const float shi = __half2float(__ushort_as_half((unsigned short)(s[j] >> 16)));
            if (j & 1) { bx += v * slo; by += v * shi; }
            else       { ax += v * slo; ay += v * shi; }
        }
    }
    for (; e < end; ++e) {
        const unsigned r = rec4[e];
        const unsigned s = support_u[(size_t)(r >> 15) * 64 + lane];
        const float v = __half2float(__ushort_as_half((unsigned short)(r & 0x7FFFu)));
        ax += v * __half2float(__ushort_as_half((unsigned short)(s & 0xFFFFu)));
        ay += v * __half2float(__ushort_as_half((unsigned short)(s >> 16)));
    }

    // non-temporal: don't let the 50MB out stream evict support rows from L2
    floatx2 res;
    res.x = tanhf(ax + bx);
    res.y = tanhf(ay + by);
    floatx2* out2 = (floatx2*)out;
    __builtin_nontemporal_store(res, &out2[(size_t)node * 64 + lane]);
}

extern "C" void kernel_launch(void* const* d_in, const int* in_sizes, int n_in,
                              void* d_out, int out_size, void* d_ws, size_t ws_size,
                              hipStream_t stream) {
    const float* x    = (const float*)d_in[0];
    const float* W    = (const float*)d_in[1];
    const int*   erow = (const int*)d_in[2];
    const int*   ecol = (const int*)d_in[3];
    const float* eval = (const float*)d_in[4];
    float* out = (float*)d_out;

    const int n_nodes = in_sizes[0] / D;   // 100000
    const int n_edges = in_sizes[2];       // 1600000
    const int nbins = (n_nodes + BIN_ROWS - 1) >> BIN_SHIFT;      // 391

    // Workspace layout (16B alignment preserved per chunk)
    unsigned short* support2 = (unsigned short*)d_ws;             // 25.6 MB
    unsigned short* wt = support2 + (size_t)n_nodes * D;          // 32 KB
    uint2* tmp8   = (uint2*)(wt + D * D);                         // 12.8 MB
    unsigned int* rec4 = (unsigned int*)(tmp8 + n_edges);         // 6.4 MB
    int*  offsets = (int*)(rec4 + n_edges);                       // n_nodes+1
    int*  cbin    = offsets + n_nodes + 1;                        // NB_MAX
    int*  cbase   = cbin + NB_MAX;                                // NB_MAX+1
    int*  ccur    = cbase + NB_MAX + 1;                           // nbins*CPAD

    // 1) wt = f16(W^T) (+ zero coarse-bin counters); support = fp16(x @ W)
    gcn_wt_kernel<<<(D * D) / 256, 256, 0, stream>>>(W, wt, cbin);
    gcn_gemm_kernel<<<(n_nodes + 127) / 128, 256, 0, stream>>>(
        x, wt, support2, n_nodes);

    // 2) coarse-bin histogram + tiny scan
    gcn_chist_kernel<<<320, 256, 0, stream>>>(erow, cbin, n_edges);
    gcn_cscan_kernel<<<1, 512, 0, stream>>>(cbin, cbase, ccur, offsets,
                                            nbins, n_nodes, n_edges);

    // 3) two-stage binned CSR build
    gcn_binA_kernel<<<(n_edges + AW - 1) / AW, 512, 0, stream>>>(
        erow, ecol, eval, ccur, tmp8, n_edges, nbins);
    gcn_binB_kernel<<<nbins, 256, 0, stream>>>(tmp8, cbase, offsets, rec4, n_nodes);

    // 4) per-node reduce + fused tanh
    gcn_gather_kernel<<<(n_nodes + 3) / 4, 256, 0, stream>>>(
        (const unsigned int*)support2, rec4, offsets, out, n_nodes);
}